// Round 1
// baseline (1145.468 us; speedup 1.0000x reference)
//
#include <hip/hip_runtime.h>
#include <hip/hip_bf16.h>

// Problem constants (B=1)
#define N_TOK 8192
#define DIM   1024
#define NEXP  8
#define FF    4096
#define CAP   2560            // int(8192*2*1.25/8)
#define NASSIGN (N_TOK * 2)   // K=2, slot-major: j = s*N + t

typedef __bf16 bf16;
typedef __bf16 bf16x8 __attribute__((ext_vector_type(8)));
typedef float  f32x4  __attribute__((ext_vector_type(4)));

// ---------------------------------------------------------------------------
// fp32 -> bf16 weight conversion (grid-stride, 8 elems/thread)
// ---------------------------------------------------------------------------
__global__ __launch_bounds__(256) void cvt_bf16_kernel(const float* __restrict__ in,
                                                       bf16* __restrict__ out, int n) {
    int stride = gridDim.x * blockDim.x * 8;
    for (int i = (blockIdx.x * blockDim.x + threadIdx.x) * 8; i < n; i += stride) {
        float4 a = *(const float4*)(in + i);
        float4 b = *(const float4*)(in + i + 4);
        bf16x8 o;
        o[0] = (bf16)a.x; o[1] = (bf16)a.y; o[2] = (bf16)a.z; o[3] = (bf16)a.w;
        o[4] = (bf16)b.x; o[5] = (bf16)b.y; o[6] = (bf16)b.z; o[7] = (bf16)b.w;
        *(bf16x8*)(out + i) = o;
    }
}

// ---------------------------------------------------------------------------
// Router: logits in fp64 (top-k selection robustness), softmax, top-2.
// One wave per token.
// ---------------------------------------------------------------------------
__global__ __launch_bounds__(256) void router_kernel(const float* __restrict__ x,
                                                     const float* __restrict__ Wr,
                                                     float* __restrict__ probs,
                                                     int* __restrict__ topi,
                                                     float* __restrict__ topw) {
    int wave = threadIdx.x >> 6;
    int lane = threadIdx.x & 63;
    int t = blockIdx.x * 4 + wave;
    const float* xr = x + (size_t)t * DIM;

    double acc[NEXP];
#pragma unroll
    for (int e = 0; e < NEXP; ++e) acc[e] = 0.0;
    for (int i = lane; i < DIM; i += 64) {
        double xv = (double)xr[i];
#pragma unroll
        for (int e = 0; e < NEXP; ++e) acc[e] += xv * (double)Wr[e * DIM + i];
    }
#pragma unroll
    for (int e = 0; e < NEXP; ++e) {
        double v = acc[e];
        for (int off = 32; off > 0; off >>= 1) v += __shfl_down(v, off, 64);
        acc[e] = v;  // valid on lane 0
    }
    if (lane == 0) {
        double mx = acc[0];
        for (int e = 1; e < NEXP; ++e) if (acc[e] > mx) mx = acc[e];
        double p[NEXP], s = 0.0;
        for (int e = 0; e < NEXP; ++e) { p[e] = exp(acc[e] - mx); s += p[e]; }
        float pf[NEXP];
        for (int e = 0; e < NEXP; ++e) { pf[e] = (float)(p[e] / s); probs[t * NEXP + e] = pf[e]; }
        // top-2 on logits (same order as probs); ties -> lowest index (strict >)
        int e1 = 0;
        for (int e = 1; e < NEXP; ++e) if (acc[e] > acc[e1]) e1 = e;
        int e2 = -1;
        for (int e = 0; e < NEXP; ++e) {
            if (e == e1) continue;
            if (e2 < 0 || acc[e] > acc[e2]) e2 = e;
        }
        float w1 = pf[e1], w2 = pf[e2];
        float inv = 1.0f / (w1 + w2 + 1e-9f);
        topi[t * 2 + 0] = e1; topi[t * 2 + 1] = e2;
        topw[t * 2 + 0] = w1 * inv; topw[t * 2 + 1] = w2 * inv;
    }
}

// ---------------------------------------------------------------------------
// Rank/capacity in exact slot-major reference order. One block (1 wave) per
// expert; lane L owns assignments [L*256, (L+1)*256); exclusive wave scan
// gives the global arrival rank.
// ---------------------------------------------------------------------------
__global__ __launch_bounds__(64) void rank_kernel(const int* __restrict__ topi,
                                                  int* __restrict__ dest,
                                                  int* __restrict__ accf,
                                                  int* __restrict__ counts) {
    int e = blockIdx.x;
    int lane = threadIdx.x;
    const int per = NASSIGN / 64;  // 256
    int base = lane * per;
    int cnt = 0;
    for (int i = 0; i < per; ++i) {
        int j = base + i;
        int t = j & (N_TOK - 1), s = j >> 13;
        if (topi[t * 2 + s] == e) cnt++;
    }
    int sum = cnt;
    for (int off = 1; off < 64; off <<= 1) {
        int v = __shfl_up(sum, off, 64);
        if (lane >= off) sum += v;
    }
    int r = sum - cnt;                       // exclusive prefix
    int total = __shfl(sum, 63, 64);
    for (int i = 0; i < per; ++i) {
        int j = base + i;
        int t = j & (N_TOK - 1), s = j >> 13;
        if (topi[t * 2 + s] == e) {
            int acc = (r < CAP) ? 1 : 0;
            dest[j] = e * CAP + (acc ? r : 0);
            accf[j] = acc;
            r++;
        }
    }
    if (lane == 63) counts[e] = (total < CAP) ? total : CAP;
}

// ---------------------------------------------------------------------------
// Gather: x row -> bf16 capacity buffer row. One block per assignment.
// ---------------------------------------------------------------------------
__global__ __launch_bounds__(256) void gather_kernel(const float* __restrict__ x,
                                                     const int* __restrict__ dest,
                                                     const int* __restrict__ accf,
                                                     bf16* __restrict__ Xe) {
    int j = blockIdx.x;
    if (!accf[j]) return;
    int t = j & (N_TOK - 1);
    int d0 = threadIdx.x * 4;
    float4 v = *(const float4*)(x + (size_t)t * DIM + d0);
    union { bf16 h[4]; uint2 u; } tmp;
    tmp.h[0] = (bf16)v.x; tmp.h[1] = (bf16)v.y; tmp.h[2] = (bf16)v.z; tmp.h[3] = (bf16)v.w;
    *(uint2*)(Xe + (size_t)dest[j] * DIM + d0) = tmp.u;
}

// ---------------------------------------------------------------------------
// GEMM tile geometry (both GEMMs): 128x128 tile, BK=64, 256 thr = 4 waves,
// each wave 64x64 (4x4 frags of 16x16x32 bf16 MFMA).
// LDS layout: [row][8 chunks of 8 bf16], chunk XOR-swizzled: phys = c ^ (row&7)
// -> b128 reads/writes hit all 32 banks (optimal 8-cycle wave service).
// MFMA layouts (guide §3): A: row=lane&15, k=(lane>>4)*8+j ; B: col=lane&15,
// same k ; C/D: col=lane&15, row=(lane>>4)*4+reg.
// ---------------------------------------------------------------------------
__global__ __launch_bounds__(256, 2) void gateup_kernel(const bf16* __restrict__ Xe,
                                                        const bf16* __restrict__ Wg,
                                                        const bf16* __restrict__ Wu,
                                                        bf16* __restrict__ hbuf) {
    const int e = blockIdx.z;
    const int m0 = blockIdx.x * 128;   // token rows (within expert capacity)
    const int n0 = blockIdx.y * 128;   // FF cols
    const int tid = threadIdx.x;
    const int lane = tid & 63;
    const int wave = tid >> 6;
    const int wr = wave >> 1, wc = wave & 1;
    const int r16 = lane & 15, c16 = lane >> 4;

    __shared__ bf16 As[128 * 64];
    __shared__ bf16 Bgs[128 * 64];
    __shared__ bf16 Bus[128 * 64];

    // staging: 1024 16B-chunks per tile, 4 per thread
    int soff[4];
    const bf16 *pa[4], *pg[4], *pu[4];
#pragma unroll
    for (int i = 0; i < 4; ++i) {
        int g = tid + i * 256;
        int row = g >> 3, c = g & 7;
        soff[i] = row * 64 + ((c ^ (row & 7)) * 8);
        pa[i] = Xe + (size_t)e * CAP * DIM + (size_t)(m0 + row) * DIM + c * 8;
        pg[i] = Wg + (size_t)e * FF * DIM + (size_t)(n0 + row) * DIM + c * 8;
        pu[i] = Wu + (size_t)e * FF * DIM + (size_t)(n0 + row) * DIM + c * 8;
    }

    f32x4 accg[4][4] = {};
    f32x4 accu[4][4] = {};

    for (int kt = 0; kt < DIM / 64; ++kt) {
#pragma unroll
        for (int i = 0; i < 4; ++i) {
            *(bf16x8*)&As[soff[i]]  = *(const bf16x8*)pa[i];
            *(bf16x8*)&Bgs[soff[i]] = *(const bf16x8*)pg[i];
            *(bf16x8*)&Bus[soff[i]] = *(const bf16x8*)pu[i];
            pa[i] += 64; pg[i] += 64; pu[i] += 64;
        }
        __syncthreads();
#pragma unroll
        for (int kk = 0; kk < 2; ++kk) {
            bf16x8 a[4], bg[4], bu[4];
#pragma unroll
            for (int m = 0; m < 4; ++m) {
                int row = wr * 64 + m * 16 + r16;
                int phys = (kk * 4 + c16) ^ (row & 7);
                a[m] = *(const bf16x8*)&As[row * 64 + phys * 8];
            }
#pragma unroll
            for (int n = 0; n < 4; ++n) {
                int row = wc * 64 + n * 16 + r16;
                int phys = (kk * 4 + c16) ^ (row & 7);
                bg[n] = *(const bf16x8*)&Bgs[row * 64 + phys * 8];
                bu[n] = *(const bf16x8*)&Bus[row * 64 + phys * 8];
            }
#pragma unroll
            for (int m = 0; m < 4; ++m)
#pragma unroll
                for (int n = 0; n < 4; ++n) {
                    accg[m][n] = __builtin_amdgcn_mfma_f32_16x16x32_bf16(a[m], bg[n], accg[m][n], 0, 0, 0);
                    accu[m][n] = __builtin_amdgcn_mfma_f32_16x16x32_bf16(a[m], bu[n], accu[m][n], 0, 0, 0);
                }
        }
        __syncthreads();
    }

    // epilogue: h = silu(gate) * up -> bf16
    bf16* hp = hbuf + (size_t)e * CAP * FF;
#pragma unroll
    for (int m = 0; m < 4; ++m)
#pragma unroll
        for (int n = 0; n < 4; ++n)
#pragma unroll
            for (int j = 0; j < 4; ++j) {
                float g = accg[m][n][j];
                float u = accu[m][n][j];
                float h = (g / (1.f + __expf(-g))) * u;
                int gr = m0 + wr * 64 + m * 16 + c16 * 4 + j;
                int gc = n0 + wc * 64 + n * 16 + r16;
                hp[(size_t)gr * FF + gc] = (bf16)h;
            }
}

__global__ __launch_bounds__(256, 2) void down_kernel(const bf16* __restrict__ hbuf,
                                                      const bf16* __restrict__ Wd,
                                                      float* __restrict__ eo) {
    const int e = blockIdx.z;
    const int m0 = blockIdx.x * 128;   // token rows
    const int n0 = blockIdx.y * 128;   // D cols
    const int tid = threadIdx.x;
    const int lane = tid & 63;
    const int wave = tid >> 6;
    const int wr = wave >> 1, wc = wave & 1;
    const int r16 = lane & 15, c16 = lane >> 4;

    __shared__ bf16 As[128 * 64];
    __shared__ bf16 Bs[128 * 64];

    int soff[4];
    const bf16 *pa[4], *pb[4];
#pragma unroll
    for (int i = 0; i < 4; ++i) {
        int g = tid + i * 256;
        int row = g >> 3, c = g & 7;
        soff[i] = row * 64 + ((c ^ (row & 7)) * 8);
        pa[i] = hbuf + (size_t)e * CAP * FF + (size_t)(m0 + row) * FF + c * 8;
        pb[i] = Wd + (size_t)e * DIM * FF + (size_t)(n0 + row) * FF + c * 8;
    }

    f32x4 acc[4][4] = {};

    for (int kt = 0; kt < FF / 64; ++kt) {
#pragma unroll
        for (int i = 0; i < 4; ++i) {
            *(bf16x8*)&As[soff[i]] = *(const bf16x8*)pa[i];
            *(bf16x8*)&Bs[soff[i]] = *(const bf16x8*)pb[i];
            pa[i] += 64; pb[i] += 64;
        }
        __syncthreads();
#pragma unroll
        for (int kk = 0; kk < 2; ++kk) {
            bf16x8 a[4], b[4];
#pragma unroll
            for (int m = 0; m < 4; ++m) {
                int row = wr * 64 + m * 16 + r16;
                int phys = (kk * 4 + c16) ^ (row & 7);
                a[m] = *(const bf16x8*)&As[row * 64 + phys * 8];
            }
#pragma unroll
            for (int n = 0; n < 4; ++n) {
                int row = wc * 64 + n * 16 + r16;
                int phys = (kk * 4 + c16) ^ (row & 7);
                b[n] = *(const bf16x8*)&Bs[row * 64 + phys * 8];
            }
#pragma unroll
            for (int m = 0; m < 4; ++m)
#pragma unroll
                for (int n = 0; n < 4; ++n)
                    acc[m][n] = __builtin_amdgcn_mfma_f32_16x16x32_bf16(a[m], b[n], acc[m][n], 0, 0, 0);
        }
        __syncthreads();
    }

    float* op = eo + (size_t)e * CAP * DIM;
#pragma unroll
    for (int m = 0; m < 4; ++m)
#pragma unroll
        for (int n = 0; n < 4; ++n)
#pragma unroll
            for (int j = 0; j < 4; ++j) {
                int gr = m0 + wr * 64 + m * 16 + c16 * 4 + j;
                int gc = n0 + wc * 64 + n * 16 + r16;
                op[(size_t)gr * DIM + gc] = acc[m][n][j];
            }
}

// ---------------------------------------------------------------------------
// Combine: out[t] = sum_s w_ts * accepted_ts * eo[dest_ts]. One block/token.
// ---------------------------------------------------------------------------
__global__ __launch_bounds__(256) void combine_kernel(const float* __restrict__ eo,
                                                      const int* __restrict__ dest,
                                                      const int* __restrict__ accf,
                                                      const float* __restrict__ topw,
                                                      float* __restrict__ out) {
    int t = blockIdx.x;
    float w0 = accf[t] ? topw[t * 2 + 0] : 0.f;           // slot 0: j = t
    float w1 = accf[N_TOK + t] ? topw[t * 2 + 1] : 0.f;   // slot 1: j = N + t
    const float* r0 = eo + (size_t)dest[t] * DIM;
    const float* r1 = eo + (size_t)dest[N_TOK + t] * DIM;
    int d = threadIdx.x * 4;
    float4 a = *(const float4*)(r0 + d);
    float4 b = *(const float4*)(r1 + d);
    float4 o;
    o.x = w0 * a.x + w1 * b.x;
    o.y = w0 * a.y + w1 * b.y;
    o.z = w0 * a.z + w1 * b.z;
    o.w = w0 * a.w + w1 * b.w;
    *(float4*)(out + (size_t)t * DIM + d) = o;
}

// ---------------------------------------------------------------------------
// Aux loss: deterministic fixed-tree reduction of probs mean + counts.
// ---------------------------------------------------------------------------
__global__ __launch_bounds__(256) void aux_kernel(const float* __restrict__ probs,
                                                  const int* __restrict__ counts,
                                                  float* __restrict__ out_aux) {
    __shared__ float sm[256][NEXP];
    float loc[NEXP];
#pragma unroll
    for (int e = 0; e < NEXP; ++e) loc[e] = 0.f;
    for (int t = threadIdx.x; t < N_TOK; t += 256)
#pragma unroll
        for (int e = 0; e < NEXP; ++e) loc[e] += probs[t * NEXP + e];
#pragma unroll
    for (int e = 0; e < NEXP; ++e) sm[threadIdx.x][e] = loc[e];
    __syncthreads();
    for (int s = 128; s > 0; s >>= 1) {
        if (threadIdx.x < s)
#pragma unroll
            for (int e = 0; e < NEXP; ++e) sm[threadIdx.x][e] += sm[threadIdx.x + s][e];
        __syncthreads();
    }
    if (threadIdx.x == 0) {
        int tot = 0;
        for (int e = 0; e < NEXP; ++e) tot += counts[e];
        float totf = tot > 0 ? (float)tot : 1.f;
        float aux = 0.f;
        for (int e = 0; e < NEXP; ++e)
            aux += ((float)counts[e] / totf) * (sm[0][e] / (float)N_TOK);
        out_aux[0] = 0.01f * (float)NEXP * aux;
    }
}

// ---------------------------------------------------------------------------
extern "C" void kernel_launch(void* const* d_in, const int* in_sizes, int n_in,
                              void* d_out, int out_size, void* d_ws, size_t ws_size,
                              hipStream_t stream) {
    const float* x  = (const float*)d_in[0];
    const float* Wr = (const float*)d_in[1];
    const float* Wg = (const float*)d_in[2];
    const float* Wu = (const float*)d_in[3];
    const float* Wd = (const float*)d_in[4];
    float* out = (float*)d_out;

    char* ws = (char*)d_ws;
    size_t off = 0;
    auto alloc = [&](size_t bytes) -> void* {
        void* p = ws + off;
        off += (bytes + 255) & ~(size_t)255;
        return p;
    };
    const size_t NW = (size_t)NEXP * FF * DIM;  // 33,554,432 per weight tensor
    bf16*  Wg_bf = (bf16*)alloc(NW * sizeof(bf16));
    bf16*  Wu_bf = (bf16*)alloc(NW * sizeof(bf16));
    bf16*  Wd_bf = (bf16*)alloc(NW * sizeof(bf16));
    bf16*  Xe    = (bf16*)alloc((size_t)NEXP * CAP * DIM * sizeof(bf16));
    bf16*  hbuf  = (bf16*)alloc((size_t)NEXP * CAP * FF * sizeof(bf16));
    float* eo    = (float*)alloc((size_t)NEXP * CAP * DIM * sizeof(float));
    float* probs = (float*)alloc((size_t)N_TOK * NEXP * sizeof(float));
    int*   topi  = (int*)alloc((size_t)N_TOK * 2 * sizeof(int));
    float* topw  = (float*)alloc((size_t)N_TOK * 2 * sizeof(float));
    int*   dst   = (int*)alloc((size_t)NASSIGN * sizeof(int));
    int*   accf  = (int*)alloc((size_t)NASSIGN * sizeof(int));
    int*   cnts  = (int*)alloc(NEXP * sizeof(int));

    cvt_bf16_kernel<<<2048, 256, 0, stream>>>(Wg, Wg_bf, (int)NW);
    cvt_bf16_kernel<<<2048, 256, 0, stream>>>(Wu, Wu_bf, (int)NW);
    cvt_bf16_kernel<<<2048, 256, 0, stream>>>(Wd, Wd_bf, (int)NW);
    router_kernel<<<N_TOK / 4, 256, 0, stream>>>(x, Wr, probs, topi, topw);
    rank_kernel<<<NEXP, 64, 0, stream>>>(topi, dst, accf, cnts);
    gather_kernel<<<NASSIGN, 256, 0, stream>>>(x, dst, accf, Xe);
    gateup_kernel<<<dim3(CAP / 128, FF / 128, NEXP), 256, 0, stream>>>(Xe, Wg_bf, Wu_bf, hbuf);
    down_kernel<<<dim3(CAP / 128, DIM / 128, NEXP), 256, 0, stream>>>(hbuf, Wd_bf, eo);
    combine_kernel<<<N_TOK, 256, 0, stream>>>(eo, dst, accf, topw, out);
    aux_kernel<<<1, 256, 0, stream>>>(probs, cnts, out + (size_t)N_TOK * DIM);
}

// Round 2
// 1003.301 us; speedup vs baseline: 1.1417x; 1.1417x over previous
//
#include <hip/hip_runtime.h>
#include <hip/hip_bf16.h>

// Problem constants (B=1)
#define N_TOK 8192
#define DIM   1024
#define NEXP  8
#define FF    4096
#define CAP   2560            // int(8192*2*1.25/8)
#define NASSIGN (N_TOK * 2)   // K=2, slot-major: j = s*N + t

typedef __bf16 bf16;
typedef __bf16 bf16x8 __attribute__((ext_vector_type(8)));
typedef float  f32x4  __attribute__((ext_vector_type(4)));

// async global->LDS DMA, 16B per lane. LDS dest = wave-uniform base + lane*16.
__device__ __forceinline__ void gl2lds16(const bf16* g, bf16* l) {
    __builtin_amdgcn_global_load_lds(
        (const __attribute__((address_space(1))) unsigned int*)g,
        (__attribute__((address_space(3))) unsigned int*)l,
        16, 0, 0);
}

// ---------------------------------------------------------------------------
// fp32 -> bf16 weight conversion (grid-stride, 8 elems/thread)
// ---------------------------------------------------------------------------
__global__ __launch_bounds__(256) void cvt_bf16_kernel(const float* __restrict__ in,
                                                       bf16* __restrict__ out, int n) {
    int stride = gridDim.x * blockDim.x * 8;
    for (int i = (blockIdx.x * blockDim.x + threadIdx.x) * 8; i < n; i += stride) {
        float4 a = *(const float4*)(in + i);
        float4 b = *(const float4*)(in + i + 4);
        bf16x8 o;
        o[0] = (bf16)a.x; o[1] = (bf16)a.y; o[2] = (bf16)a.z; o[3] = (bf16)a.w;
        o[4] = (bf16)b.x; o[5] = (bf16)b.y; o[6] = (bf16)b.z; o[7] = (bf16)b.w;
        *(bf16x8*)(out + i) = o;
    }
}

// ---------------------------------------------------------------------------
// Router: logits in fp64 (top-k selection robustness), softmax, top-2.
// ---------------------------------------------------------------------------
__global__ __launch_bounds__(256) void router_kernel(const float* __restrict__ x,
                                                     const float* __restrict__ Wr,
                                                     float* __restrict__ probs,
                                                     int* __restrict__ topi,
                                                     float* __restrict__ topw) {
    int wave = threadIdx.x >> 6;
    int lane = threadIdx.x & 63;
    int t = blockIdx.x * 4 + wave;
    const float* xr = x + (size_t)t * DIM;

    double acc[NEXP];
#pragma unroll
    for (int e = 0; e < NEXP; ++e) acc[e] = 0.0;
    for (int i = lane; i < DIM; i += 64) {
        double xv = (double)xr[i];
#pragma unroll
        for (int e = 0; e < NEXP; ++e) acc[e] += xv * (double)Wr[e * DIM + i];
    }
#pragma unroll
    for (int e = 0; e < NEXP; ++e) {
        double v = acc[e];
        for (int off = 32; off > 0; off >>= 1) v += __shfl_down(v, off, 64);
        acc[e] = v;  // valid on lane 0
    }
    if (lane == 0) {
        double mx = acc[0];
        for (int e = 1; e < NEXP; ++e) if (acc[e] > mx) mx = acc[e];
        double p[NEXP], s = 0.0;
        for (int e = 0; e < NEXP; ++e) { p[e] = exp(acc[e] - mx); s += p[e]; }
        float pf[NEXP];
        for (int e = 0; e < NEXP; ++e) { pf[e] = (float)(p[e] / s); probs[t * NEXP + e] = pf[e]; }
        int e1 = 0;
        for (int e = 1; e < NEXP; ++e) if (acc[e] > acc[e1]) e1 = e;
        int e2 = -1;
        for (int e = 0; e < NEXP; ++e) {
            if (e == e1) continue;
            if (e2 < 0 || acc[e] > acc[e2]) e2 = e;
        }
        float w1 = pf[e1], w2 = pf[e2];
        float inv = 1.0f / (w1 + w2 + 1e-9f);
        topi[t * 2 + 0] = e1; topi[t * 2 + 1] = e2;
        topw[t * 2 + 0] = w1 * inv; topw[t * 2 + 1] = w2 * inv;
    }
}

// ---------------------------------------------------------------------------
// Rank/capacity in exact slot-major reference order. One wave per expert.
// ---------------------------------------------------------------------------
__global__ __launch_bounds__(64) void rank_kernel(const int* __restrict__ topi,
                                                  int* __restrict__ dest,
                                                  int* __restrict__ accf,
                                                  int* __restrict__ counts) {
    int e = blockIdx.x;
    int lane = threadIdx.x;
    const int per = NASSIGN / 64;  // 256
    int base = lane * per;
    int cnt = 0;
    for (int i = 0; i < per; ++i) {
        int j = base + i;
        int t = j & (N_TOK - 1), s = j >> 13;
        if (topi[t * 2 + s] == e) cnt++;
    }
    int sum = cnt;
    for (int off = 1; off < 64; off <<= 1) {
        int v = __shfl_up(sum, off, 64);
        if (lane >= off) sum += v;
    }
    int r = sum - cnt;                       // exclusive prefix
    int total = __shfl(sum, 63, 64);
    for (int i = 0; i < per; ++i) {
        int j = base + i;
        int t = j & (N_TOK - 1), s = j >> 13;
        if (topi[t * 2 + s] == e) {
            int acc = (r < CAP) ? 1 : 0;
            dest[j] = e * CAP + (acc ? r : 0);
            accf[j] = acc;
            r++;
        }
    }
    if (lane == 63) counts[e] = (total < CAP) ? total : CAP;
}

// ---------------------------------------------------------------------------
// Gather: x row -> bf16 capacity buffer row. One block per assignment.
// ---------------------------------------------------------------------------
__global__ __launch_bounds__(256) void gather_kernel(const float* __restrict__ x,
                                                     const int* __restrict__ dest,
                                                     const int* __restrict__ accf,
                                                     bf16* __restrict__ Xe) {
    int j = blockIdx.x;
    if (!accf[j]) return;
    int t = j & (N_TOK - 1);
    int d0 = threadIdx.x * 4;
    float4 v = *(const float4*)(x + (size_t)t * DIM + d0);
    union { bf16 h[4]; uint2 u; } tmp;
    tmp.h[0] = (bf16)v.x; tmp.h[1] = (bf16)v.y; tmp.h[2] = (bf16)v.z; tmp.h[3] = (bf16)v.w;
    *(uint2*)(Xe + (size_t)dest[j] * DIM + d0) = tmp.u;
}

// ---------------------------------------------------------------------------
// GEMM tile geometry (both GEMMs): 128x128 tile, BK=64, 256 thr = 4 waves,
// each wave 64x64 (4x4 frags of 16x16x32 bf16 MFMA).
// Staging: global_load_lds width=16, LINEAR LDS dest (rule: both-sides-or-
// neither). Chunk swizzle (phys = c ^ (row&7)) is applied by PRE-SWIZZLING the
// per-lane GLOBAL source chunk; ds_read applies the same XOR. Involution, so
// source perm == read perm.
// Per wave, call q stages rows [q*8, q*8+8): lane l -> row q*8+(l>>3),
// phys chunk l&7, global chunk (l&7)^(row&7).
// ---------------------------------------------------------------------------
__global__ __launch_bounds__(256, 3) void gateup_kernel(const bf16* __restrict__ Xe,
                                                        const bf16* __restrict__ Wg,
                                                        const bf16* __restrict__ Wu,
                                                        bf16* __restrict__ hbuf) {
    const int e = blockIdx.z;
    const int m0 = blockIdx.x * 128;   // token rows
    const int n0 = blockIdx.y * 128;   // FF cols
    const int tid = threadIdx.x;
    const int lane = tid & 63;
    const int wave = tid >> 6;
    const int wr = wave >> 1, wc = wave & 1;
    const int r16 = lane & 15, c16 = lane >> 4;

    __shared__ bf16 As[128 * 64];
    __shared__ bf16 Bgs[128 * 64];
    __shared__ bf16 Bus[128 * 64];

    // per-lane pre-swizzled global sources; 4 calls per wave per tile
    const bf16 *pa[4], *pg[4], *pu[4];
    bf16 *la[4], *lg[4], *lu[4];
#pragma unroll
    for (int i = 0; i < 4; ++i) {
        int q = wave * 4 + i;
        int row = q * 8 + (lane >> 3);
        int c = (lane & 7) ^ (row & 7);       // pre-swizzled source chunk
        pa[i] = Xe + (size_t)e * CAP * DIM + (size_t)(m0 + row) * DIM + c * 8;
        pg[i] = Wg + (size_t)e * FF * DIM + (size_t)(n0 + row) * DIM + c * 8;
        pu[i] = Wu + (size_t)e * FF * DIM + (size_t)(n0 + row) * DIM + c * 8;
        la[i] = As  + q * 512;                // wave-uniform linear dest
        lg[i] = Bgs + q * 512;
        lu[i] = Bus + q * 512;
    }

    f32x4 accg[4][4] = {};
    f32x4 accu[4][4] = {};

    for (int kt = 0; kt < DIM / 64; ++kt) {
#pragma unroll
        for (int i = 0; i < 4; ++i) {
            gl2lds16(pa[i], la[i]);
            gl2lds16(pg[i], lg[i]);
            gl2lds16(pu[i], lu[i]);
            pa[i] += 64; pg[i] += 64; pu[i] += 64;
        }
        __syncthreads();   // drains vmcnt -> staged data visible
#pragma unroll
        for (int kk = 0; kk < 2; ++kk) {
            bf16x8 a[4];
#pragma unroll
            for (int m = 0; m < 4; ++m) {
                int row = wr * 64 + m * 16 + r16;
                int phys = (kk * 4 + c16) ^ (row & 7);
                a[m] = *(const bf16x8*)&As[row * 64 + phys * 8];
            }
#pragma unroll
            for (int n = 0; n < 4; ++n) {
                int row = wc * 64 + n * 16 + r16;
                int phys = (kk * 4 + c16) ^ (row & 7);
                bf16x8 bg = *(const bf16x8*)&Bgs[row * 64 + phys * 8];
                bf16x8 bu = *(const bf16x8*)&Bus[row * 64 + phys * 8];
#pragma unroll
                for (int m = 0; m < 4; ++m) {
                    accg[m][n] = __builtin_amdgcn_mfma_f32_16x16x32_bf16(a[m], bg, accg[m][n], 0, 0, 0);
                    accu[m][n] = __builtin_amdgcn_mfma_f32_16x16x32_bf16(a[m], bu, accu[m][n], 0, 0, 0);
                }
            }
        }
        __syncthreads();
    }

    // epilogue: h = silu(gate) * up -> bf16
    bf16* hp = hbuf + (size_t)e * CAP * FF;
#pragma unroll
    for (int m = 0; m < 4; ++m)
#pragma unroll
        for (int n = 0; n < 4; ++n)
#pragma unroll
            for (int j = 0; j < 4; ++j) {
                float g = accg[m][n][j];
                float u = accu[m][n][j];
                float h = (g / (1.f + __expf(-g))) * u;
                int gr = m0 + wr * 64 + m * 16 + c16 * 4 + j;
                int gc = n0 + wc * 64 + n * 16 + r16;
                hp[(size_t)gr * FF + gc] = (bf16)h;
            }
}

__global__ __launch_bounds__(256, 4) void down_kernel(const bf16* __restrict__ hbuf,
                                                      const bf16* __restrict__ Wd,
                                                      float* __restrict__ eo) {
    const int e = blockIdx.z;
    const int m0 = blockIdx.x * 128;   // token rows
    const int n0 = blockIdx.y * 128;   // D cols
    const int tid = threadIdx.x;
    const int lane = tid & 63;
    const int wave = tid >> 6;
    const int wr = wave >> 1, wc = wave & 1;
    const int r16 = lane & 15, c16 = lane >> 4;

    __shared__ bf16 As[128 * 64];
    __shared__ bf16 Bs[128 * 64];

    const bf16 *pa[4], *pb[4];
    bf16 *la[4], *lb[4];
#pragma unroll
    for (int i = 0; i < 4; ++i) {
        int q = wave * 4 + i;
        int row = q * 8 + (lane >> 3);
        int c = (lane & 7) ^ (row & 7);
        pa[i] = hbuf + (size_t)e * CAP * FF + (size_t)(m0 + row) * FF + c * 8;
        pb[i] = Wd + (size_t)e * DIM * FF + (size_t)(n0 + row) * FF + c * 8;
        la[i] = As + q * 512;
        lb[i] = Bs + q * 512;
    }

    f32x4 acc[4][4] = {};

    for (int kt = 0; kt < FF / 64; ++kt) {
#pragma unroll
        for (int i = 0; i < 4; ++i) {
            gl2lds16(pa[i], la[i]);
            gl2lds16(pb[i], lb[i]);
            pa[i] += 64; pb[i] += 64;
        }
        __syncthreads();
#pragma unroll
        for (int kk = 0; kk < 2; ++kk) {
            bf16x8 a[4];
#pragma unroll
            for (int m = 0; m < 4; ++m) {
                int row = wr * 64 + m * 16 + r16;
                int phys = (kk * 4 + c16) ^ (row & 7);
                a[m] = *(const bf16x8*)&As[row * 64 + phys * 8];
            }
#pragma unroll
            for (int n = 0; n < 4; ++n) {
                int row = wc * 64 + n * 16 + r16;
                int phys = (kk * 4 + c16) ^ (row & 7);
                bf16x8 b = *(const bf16x8*)&Bs[row * 64 + phys * 8];
#pragma unroll
                for (int m = 0; m < 4; ++m)
                    acc[m][n] = __builtin_amdgcn_mfma_f32_16x16x32_bf16(a[m], b, acc[m][n], 0, 0, 0);
            }
        }
        __syncthreads();
    }

    float* op = eo + (size_t)e * CAP * DIM;
#pragma unroll
    for (int m = 0; m < 4; ++m)
#pragma unroll
        for (int n = 0; n < 4; ++n)
#pragma unroll
            for (int j = 0; j < 4; ++j) {
                int gr = m0 + wr * 64 + m * 16 + c16 * 4 + j;
                int gc = n0 + wc * 64 + n * 16 + r16;
                op[(size_t)gr * DIM + gc] = acc[m][n][j];
            }
}

// ---------------------------------------------------------------------------
// Combine: out[t] = sum_s w_ts * accepted_ts * eo[dest_ts]. One block/token.
// ---------------------------------------------------------------------------
__global__ __launch_bounds__(256) void combine_kernel(const float* __restrict__ eo,
                                                      const int* __restrict__ dest,
                                                      const int* __restrict__ accf,
                                                      const float* __restrict__ topw,
                                                      float* __restrict__ out) {
    int t = blockIdx.x;
    float w0 = accf[t] ? topw[t * 2 + 0] : 0.f;           // slot 0: j = t
    float w1 = accf[N_TOK + t] ? topw[t * 2 + 1] : 0.f;   // slot 1: j = N + t
    const float* r0 = eo + (size_t)dest[t] * DIM;
    const float* r1 = eo + (size_t)dest[N_TOK + t] * DIM;
    int d = threadIdx.x * 4;
    float4 a = *(const float4*)(r0 + d);
    float4 b = *(const float4*)(r1 + d);
    float4 o;
    o.x = w0 * a.x + w1 * b.x;
    o.y = w0 * a.y + w1 * b.y;
    o.z = w0 * a.z + w1 * b.z;
    o.w = w0 * a.w + w1 * b.w;
    *(float4*)(out + (size_t)t * DIM + d) = o;
}

// ---------------------------------------------------------------------------
// Aux loss: deterministic fixed-tree reduction of probs mean + counts.
// ---------------------------------------------------------------------------
__global__ __launch_bounds__(256) void aux_kernel(const float* __restrict__ probs,
                                                  const int* __restrict__ counts,
                                                  float* __restrict__ out_aux) {
    __shared__ float sm[256][NEXP];
    float loc[NEXP];
#pragma unroll
    for (int e = 0; e < NEXP; ++e) loc[e] = 0.f;
    for (int t = threadIdx.x; t < N_TOK; t += 256)
#pragma unroll
        for (int e = 0; e < NEXP; ++e) loc[e] += probs[t * NEXP + e];
#pragma unroll
    for (int e = 0; e < NEXP; ++e) sm[threadIdx.x][e] = loc[e];
    __syncthreads();
    for (int s = 128; s > 0; s >>= 1) {
        if (threadIdx.x < s)
#pragma unroll
            for (int e = 0; e < NEXP; ++e) sm[threadIdx.x][e] += sm[threadIdx.x + s][e];
        __syncthreads();
    }
    if (threadIdx.x == 0) {
        int tot = 0;
        for (int e = 0; e < NEXP; ++e) tot += counts[e];
        float totf = tot > 0 ? (float)tot : 1.f;
        float aux = 0.f;
        for (int e = 0; e < NEXP; ++e)
            aux += ((float)counts[e] / totf) * (sm[0][e] / (float)N_TOK);
        out_aux[0] = 0.01f * (float)NEXP * aux;
    }
}

// ---------------------------------------------------------------------------
extern "C" void kernel_launch(void* const* d_in, const int* in_sizes, int n_in,
                              void* d_out, int out_size, void* d_ws, size_t ws_size,
                              hipStream_t stream) {
    const float* x  = (const float*)d_in[0];
    const float* Wr = (const float*)d_in[1];
    const float* Wg = (const float*)d_in[2];
    const float* Wu = (const float*)d_in[3];
    const float* Wd = (const float*)d_in[4];
    float* out = (float*)d_out;

    char* ws = (char*)d_ws;
    size_t off = 0;
    auto alloc = [&](size_t bytes) -> void* {
        void* p = ws + off;
        off += (bytes + 255) & ~(size_t)255;
        return p;
    };
    const size_t NW = (size_t)NEXP * FF * DIM;
    bf16*  Wg_bf = (bf16*)alloc(NW * sizeof(bf16));
    bf16*  Wu_bf = (bf16*)alloc(NW * sizeof(bf16));
    bf16*  Wd_bf = (bf16*)alloc(NW * sizeof(bf16));
    bf16*  Xe    = (bf16*)alloc((size_t)NEXP * CAP * DIM * sizeof(bf16));
    bf16*  hbuf  = (bf16*)alloc((size_t)NEXP * CAP * FF * sizeof(bf16));
    float* eo    = (float*)alloc((size_t)NEXP * CAP * DIM * sizeof(float));
    float* probs = (float*)alloc((size_t)N_TOK * NEXP * sizeof(float));
    int*   topi  = (int*)alloc((size_t)N_TOK * 2 * sizeof(int));
    float* topw  = (float*)alloc((size_t)N_TOK * 2 * sizeof(float));
    int*   dst   = (int*)alloc((size_t)NASSIGN * sizeof(int));
    int*   accf  = (int*)alloc((size_t)NASSIGN * sizeof(int));
    int*   cnts  = (int*)alloc(NEXP * sizeof(int));

    cvt_bf16_kernel<<<2048, 256, 0, stream>>>(Wg, Wg_bf, (int)NW);
    cvt_bf16_kernel<<<2048, 256, 0, stream>>>(Wu, Wu_bf, (int)NW);
    cvt_bf16_kernel<<<2048, 256, 0, stream>>>(Wd, Wd_bf, (int)NW);
    router_kernel<<<N_TOK / 4, 256, 0, stream>>>(x, Wr, probs, topi, topw);
    rank_kernel<<<NEXP, 64, 0, stream>>>(topi, dst, accf, cnts);
    gather_kernel<<<NASSIGN, 256, 0, stream>>>(x, dst, accf, Xe);
    gateup_kernel<<<dim3(CAP / 128, FF / 128, NEXP), 256, 0, stream>>>(Xe, Wg_bf, Wu_bf, hbuf);
    down_kernel<<<dim3(CAP / 128, DIM / 128, NEXP), 256, 0, stream>>>(hbuf, Wd_bf, eo);
    combine_kernel<<<N_TOK, 256, 0, stream>>>(eo, dst, accf, topw, out);
    aux_kernel<<<1, 256, 0, stream>>>(probs, cnts, out + (size_t)N_TOK * DIM);
}

// Round 4
// 912.314 us; speedup vs baseline: 1.2556x; 1.0997x over previous
//
#include <hip/hip_runtime.h>
#include <hip/hip_bf16.h>

// Problem constants (B=1)
#define N_TOK 8192
#define DIM   1024
#define NEXP  8
#define FF    4096
#define CAP   2560            // int(8192*2*1.25/8)
#define NASSIGN (N_TOK * 2)   // K=2, slot-major: j = s*N + t

typedef __bf16 bf16;
typedef __bf16 bf16x8 __attribute__((ext_vector_type(8)));
typedef float  f32x4  __attribute__((ext_vector_type(4)));

// async global->LDS DMA, 16B per lane. LDS dest = wave-uniform base + lane*16.
__device__ __forceinline__ void gl2lds16(const bf16* g, bf16* l) {
    __builtin_amdgcn_global_load_lds(
        (const __attribute__((address_space(1))) unsigned int*)g,
        (__attribute__((address_space(3))) unsigned int*)l,
        16, 0, 0);
}

// ---------------------------------------------------------------------------
// fp32 -> bf16 weight conversion
// ---------------------------------------------------------------------------
__global__ __launch_bounds__(256) void cvt_bf16_kernel(const float* __restrict__ in,
                                                       bf16* __restrict__ out, int n) {
    int stride = gridDim.x * blockDim.x * 8;
    for (int i = (blockIdx.x * blockDim.x + threadIdx.x) * 8; i < n; i += stride) {
        float4 a = *(const float4*)(in + i);
        float4 b = *(const float4*)(in + i + 4);
        bf16x8 o;
        o[0] = (bf16)a.x; o[1] = (bf16)a.y; o[2] = (bf16)a.z; o[3] = (bf16)a.w;
        o[4] = (bf16)b.x; o[5] = (bf16)b.y; o[6] = (bf16)b.z; o[7] = (bf16)b.w;
        *(bf16x8*)(out + i) = o;
    }
}

// ---------------------------------------------------------------------------
// Router: logits in fp64 (top-k selection robustness), softmax, top-2.
// ---------------------------------------------------------------------------
__global__ __launch_bounds__(256) void router_kernel(const float* __restrict__ x,
                                                     const float* __restrict__ Wr,
                                                     float* __restrict__ probs,
                                                     int* __restrict__ topi,
                                                     float* __restrict__ topw) {
    int wave = threadIdx.x >> 6;
    int lane = threadIdx.x & 63;
    int t = blockIdx.x * 4 + wave;
    const float* xr = x + (size_t)t * DIM;

    double acc[NEXP];
#pragma unroll
    for (int e = 0; e < NEXP; ++e) acc[e] = 0.0;
    for (int i = lane; i < DIM; i += 64) {
        double xv = (double)xr[i];
#pragma unroll
        for (int e = 0; e < NEXP; ++e) acc[e] += xv * (double)Wr[e * DIM + i];
    }
#pragma unroll
    for (int e = 0; e < NEXP; ++e) {
        double v = acc[e];
        for (int off = 32; off > 0; off >>= 1) v += __shfl_down(v, off, 64);
        acc[e] = v;  // valid on lane 0
    }
    if (lane == 0) {
        double mx = acc[0];
        for (int e = 1; e < NEXP; ++e) if (acc[e] > mx) mx = acc[e];
        double p[NEXP], s = 0.0;
        for (int e = 0; e < NEXP; ++e) { p[e] = exp(acc[e] - mx); s += p[e]; }
        float pf[NEXP];
        for (int e = 0; e < NEXP; ++e) { pf[e] = (float)(p[e] / s); probs[t * NEXP + e] = pf[e]; }
        int e1 = 0;
        for (int e = 1; e < NEXP; ++e) if (acc[e] > acc[e1]) e1 = e;
        int e2 = -1;
        for (int e = 0; e < NEXP; ++e) {
            if (e == e1) continue;
            if (e2 < 0 || acc[e] > acc[e2]) e2 = e;
        }
        float w1 = pf[e1], w2 = pf[e2];
        float inv = 1.0f / (w1 + w2 + 1e-9f);
        topi[t * 2 + 0] = e1; topi[t * 2 + 1] = e2;
        topw[t * 2 + 0] = w1 * inv; topw[t * 2 + 1] = w2 * inv;
    }
}

// ---------------------------------------------------------------------------
// Rank/capacity in exact slot-major reference order. One wave per expert.
// ---------------------------------------------------------------------------
__global__ __launch_bounds__(64) void rank_kernel(const int* __restrict__ topi,
                                                  int* __restrict__ dest,
                                                  int* __restrict__ accf,
                                                  int* __restrict__ counts) {
    int e = blockIdx.x;
    int lane = threadIdx.x;
    const int per = NASSIGN / 64;  // 256
    int base = lane * per;
    int cnt = 0;
    for (int i = 0; i < per; ++i) {
        int j = base + i;
        int t = j & (N_TOK - 1), s = j >> 13;
        if (topi[t * 2 + s] == e) cnt++;
    }
    int sum = cnt;
    for (int off = 1; off < 64; off <<= 1) {
        int v = __shfl_up(sum, off, 64);
        if (lane >= off) sum += v;
    }
    int r = sum - cnt;                       // exclusive prefix
    int total = __shfl(sum, 63, 64);
    for (int i = 0; i < per; ++i) {
        int j = base + i;
        int t = j & (N_TOK - 1), s = j >> 13;
        if (topi[t * 2 + s] == e) {
            int acc = (r < CAP) ? 1 : 0;
            dest[j] = e * CAP + (acc ? r : 0);
            accf[j] = acc;
            r++;
        }
    }
    if (lane == 63) counts[e] = (total < CAP) ? total : CAP;
}

// ---------------------------------------------------------------------------
// Gather: x row -> bf16 capacity buffer row. One block per assignment.
// ---------------------------------------------------------------------------
__global__ __launch_bounds__(256) void gather_kernel(const float* __restrict__ x,
                                                     const int* __restrict__ dest,
                                                     const int* __restrict__ accf,
                                                     bf16* __restrict__ Xe) {
    int j = blockIdx.x;
    if (!accf[j]) return;
    int t = j & (N_TOK - 1);
    int d0 = threadIdx.x * 4;
    float4 v = *(const float4*)(x + (size_t)t * DIM + d0);
    union { bf16 h[4]; uint2 u; } tmp;
    tmp.h[0] = (bf16)v.x; tmp.h[1] = (bf16)v.y; tmp.h[2] = (bf16)v.z; tmp.h[3] = (bf16)v.w;
    *(uint2*)(Xe + (size_t)dest[j] * DIM + d0) = tmp.u;
}

// ---------------------------------------------------------------------------
// gateup: C[256 tok x 128 cols] for BOTH gate and up (dual accumulators share
// the A tile). 8 waves as 4M x 2N, per-wave 64x64 per tensor.
// Double-buffered LDS (128 KB), counted-vmcnt schedule:
//   prologue STAGE(0),STAGE(1); per tile: vmcnt(8) [never 0 until the last
//   tile] -> s_barrier -> ds_read+MFMA phases (setprio around clusters) ->
//   s_barrier -> STAGE(kt+2) into the half just vacated.
// Swizzle: linear DMA dest; global source chunk pre-XORed with (row&7);
// ds_read applies the same XOR (involution). Staging coverage: wave w call i
// stages rows i*64 + w*8 + (lane>>3)  (A: i=0..3 -> 256 rows; B: i=0..1 ->
// 128 rows); row&7 == lane>>3.
// ---------------------------------------------------------------------------
__global__ __launch_bounds__(512, 2) void gateup_kernel(const bf16* __restrict__ Xe,
                                                        const bf16* __restrict__ Wg,
                                                        const bf16* __restrict__ Wu,
                                                        bf16* __restrict__ hbuf) {
    const int e = blockIdx.z;
    const int m0 = blockIdx.x * 256;   // token rows
    const int n0 = blockIdx.y * 128;   // FF cols (gate & up)
    const int tid = threadIdx.x;
    const int lane = tid & 63;
    const int wave = tid >> 6;         // 0..7
    const int wr = wave >> 1;          // 0..3  (row block of 64)
    const int wc = wave & 1;           // 0..1  (col block of 64)
    const int r16 = lane & 15, c16 = lane >> 4;

    __shared__ bf16 As [2][256 * 64];
    __shared__ bf16 Bgs[2][128 * 64];
    __shared__ bf16 Bus[2][128 * 64];

    const int rsub = wave * 8 + (lane >> 3);            // staging row in 64-row slab
    const int csw  = ((lane & 7) ^ (lane >> 3)) * 8;    // pre-swizzled chunk (bf16 units)
    const bf16* ga = Xe + (size_t)e * CAP * DIM + (size_t)(m0 + rsub) * DIM + csw;
    const bf16* gg = Wg + (size_t)e * FF * DIM + (size_t)(n0 + rsub) * DIM + csw;
    const bf16* gu = Wu + (size_t)e * FF * DIM + (size_t)(n0 + rsub) * DIM + csw;

    f32x4 accg[4][4] = {};
    f32x4 accu[4][4] = {};

    auto STAGE = [&](int kt) {
        const int b = kt & 1;
        const bf16* a = ga + kt * 64;
#pragma unroll
        for (int i = 0; i < 4; ++i)
            gl2lds16(a + (size_t)i * 64 * DIM, &As[b][(i * 64 + wave * 8) * 64]);
        const bf16* g = gg + kt * 64;
#pragma unroll
        for (int i = 0; i < 2; ++i)
            gl2lds16(g + (size_t)i * 64 * DIM, &Bgs[b][(i * 64 + wave * 8) * 64]);
        const bf16* u = gu + kt * 64;
#pragma unroll
        for (int i = 0; i < 2; ++i)
            gl2lds16(u + (size_t)i * 64 * DIM, &Bus[b][(i * 64 + wave * 8) * 64]);
    };

    STAGE(0);
    STAGE(1);

    for (int kt = 0; kt < DIM / 64; ++kt) {
        if (kt < DIM / 64 - 1) asm volatile("s_waitcnt vmcnt(8)" ::: "memory");
        else                   asm volatile("s_waitcnt vmcnt(0)" ::: "memory");
        __builtin_amdgcn_sched_barrier(0);
        __builtin_amdgcn_s_barrier();
        __builtin_amdgcn_sched_barrier(0);
        const int b = kt & 1;
#pragma unroll
        for (int kk = 0; kk < 2; ++kk) {
            bf16x8 a[4], bg[4], bu[4];
#pragma unroll
            for (int m = 0; m < 4; ++m) {
                int row = wr * 64 + m * 16 + r16;
                int phys = (kk * 4 + c16) ^ (row & 7);
                a[m] = *(const bf16x8*)&As[b][row * 64 + phys * 8];
            }
#pragma unroll
            for (int n = 0; n < 4; ++n) {
                int row = wc * 64 + n * 16 + r16;
                int phys = (kk * 4 + c16) ^ (row & 7);
                bg[n] = *(const bf16x8*)&Bgs[b][row * 64 + phys * 8];
            }
            __builtin_amdgcn_s_setprio(1);
#pragma unroll
            for (int m = 0; m < 4; ++m)
#pragma unroll
                for (int n = 0; n < 4; ++n)
                    accg[m][n] = __builtin_amdgcn_mfma_f32_16x16x32_bf16(a[m], bg[n], accg[m][n], 0, 0, 0);
            __builtin_amdgcn_s_setprio(0);
#pragma unroll
            for (int n = 0; n < 4; ++n) {
                int row = wc * 64 + n * 16 + r16;
                int phys = (kk * 4 + c16) ^ (row & 7);
                bu[n] = *(const bf16x8*)&Bus[b][row * 64 + phys * 8];
            }
            __builtin_amdgcn_s_setprio(1);
#pragma unroll
            for (int m = 0; m < 4; ++m)
#pragma unroll
                for (int n = 0; n < 4; ++n)
                    accu[m][n] = __builtin_amdgcn_mfma_f32_16x16x32_bf16(a[m], bu[n], accu[m][n], 0, 0, 0);
            __builtin_amdgcn_s_setprio(0);
        }
        __builtin_amdgcn_sched_barrier(0);
        __builtin_amdgcn_s_barrier();
        __builtin_amdgcn_sched_barrier(0);
        if (kt + 2 < DIM / 64) STAGE(kt + 2);
    }

    // epilogue: h = silu(gate) * up -> bf16
    bf16* hp = hbuf + (size_t)e * CAP * FF;
#pragma unroll
    for (int m = 0; m < 4; ++m)
#pragma unroll
        for (int n = 0; n < 4; ++n)
#pragma unroll
            for (int j = 0; j < 4; ++j) {
                float g = accg[m][n][j];
                float u = accu[m][n][j];
                float h = (g / (1.f + __expf(-g))) * u;
                int gr = m0 + wr * 64 + m * 16 + c16 * 4 + j;
                int gc = n0 + wc * 64 + n * 16 + r16;
                hp[(size_t)gr * FF + gc] = (bf16)h;
            }
}

// ---------------------------------------------------------------------------
// down: 128x128 tile, BK=64, 4 waves (2M x 2N, per-wave 64x64), dbuf 64 KB,
// 2 blocks/CU, same counted-vmcnt schedule.
// STAGING FIX (round-3 bug): with 4 waves, call i stages rows
// i*32 + wave*8 + (lane>>3), i=0..3 for BOTH A and B -> full 128-row
// coverage (round 3's i*64 pattern left rows 32-63 / 96-127 unwritten).
// 8 loads/wave/tile -> vmcnt(8). row&7 == lane>>3 still holds.
// ---------------------------------------------------------------------------
__global__ __launch_bounds__(256, 2) void down_kernel(const bf16* __restrict__ hbuf,
                                                      const bf16* __restrict__ Wd,
                                                      float* __restrict__ eo) {
    const int e = blockIdx.z;
    const int m0 = blockIdx.x * 128;   // token rows
    const int n0 = blockIdx.y * 128;   // D cols
    const int tid = threadIdx.x;
    const int lane = tid & 63;
    const int wave = tid >> 6;         // 0..3
    const int wr = wave >> 1;          // 0..1
    const int wc = wave & 1;           // 0..1
    const int r16 = lane & 15, c16 = lane >> 4;

    __shared__ bf16 As[2][128 * 64];
    __shared__ bf16 Bs[2][128 * 64];

    const int rsub = wave * 8 + (lane >> 3);            // [0,32)
    const int csw  = ((lane & 7) ^ (lane >> 3)) * 8;
    const bf16* gaA = hbuf + (size_t)e * CAP * FF + (size_t)(m0 + rsub) * FF + csw;
    const bf16* gaB = Wd + (size_t)e * DIM * FF + (size_t)(n0 + rsub) * FF + csw;

    f32x4 acc[4][4] = {};

    auto STAGE = [&](int kt) {
        const int b = kt & 1;
        const bf16* a = gaA + kt * 64;
#pragma unroll
        for (int i = 0; i < 4; ++i)
            gl2lds16(a + (size_t)i * 32 * FF, &As[b][(i * 32 + wave * 8) * 64]);
        const bf16* w = gaB + kt * 64;
#pragma unroll
        for (int i = 0; i < 4; ++i)
            gl2lds16(w + (size_t)i * 32 * FF, &Bs[b][(i * 32 + wave * 8) * 64]);
    };

    STAGE(0);
    STAGE(1);

    for (int kt = 0; kt < FF / 64; ++kt) {
        if (kt < FF / 64 - 1) asm volatile("s_waitcnt vmcnt(8)" ::: "memory");
        else                  asm volatile("s_waitcnt vmcnt(0)" ::: "memory");
        __builtin_amdgcn_sched_barrier(0);
        __builtin_amdgcn_s_barrier();
        __builtin_amdgcn_sched_barrier(0);
        const int b = kt & 1;
#pragma unroll
        for (int kk = 0; kk < 2; ++kk) {
            bf16x8 a[4], w[4];
#pragma unroll
            for (int m = 0; m < 4; ++m) {
                int row = wr * 64 + m * 16 + r16;
                int phys = (kk * 4 + c16) ^ (row & 7);
                a[m] = *(const bf16x8*)&As[b][row * 64 + phys * 8];
            }
#pragma unroll
            for (int n = 0; n < 4; ++n) {
                int row = wc * 64 + n * 16 + r16;
                int phys = (kk * 4 + c16) ^ (row & 7);
                w[n] = *(const bf16x8*)&Bs[b][row * 64 + phys * 8];
            }
            __builtin_amdgcn_s_setprio(1);
#pragma unroll
            for (int m = 0; m < 4; ++m)
#pragma unroll
                for (int n = 0; n < 4; ++n)
                    acc[m][n] = __builtin_amdgcn_mfma_f32_16x16x32_bf16(a[m], w[n], acc[m][n], 0, 0, 0);
            __builtin_amdgcn_s_setprio(0);
        }
        __builtin_amdgcn_sched_barrier(0);
        __builtin_amdgcn_s_barrier();
        __builtin_amdgcn_sched_barrier(0);
        if (kt + 2 < FF / 64) STAGE(kt + 2);
    }

    float* op = eo + (size_t)e * CAP * DIM;
#pragma unroll
    for (int m = 0; m < 4; ++m)
#pragma unroll
        for (int n = 0; n < 4; ++n)
#pragma unroll
            for (int j = 0; j < 4; ++j) {
                int gr = m0 + wr * 64 + m * 16 + c16 * 4 + j;
                int gc = n0 + wc * 64 + n * 16 + r16;
                op[(size_t)gr * DIM + gc] = acc[m][n][j];
            }
}

// ---------------------------------------------------------------------------
// Combine: out[t] = sum_s w_ts * accepted_ts * eo[dest_ts]. One block/token.
// ---------------------------------------------------------------------------
__global__ __launch_bounds__(256) void combine_kernel(const float* __restrict__ eo,
                                                      const int* __restrict__ dest,
                                                      const int* __restrict__ accf,
                                                      const float* __restrict__ topw,
                                                      float* __restrict__ out) {
    int t = blockIdx.x;
    float w0 = accf[t] ? topw[t * 2 + 0] : 0.f;           // slot 0: j = t
    float w1 = accf[N_TOK + t] ? topw[t * 2 + 1] : 0.f;   // slot 1: j = N + t
    const float* r0 = eo + (size_t)dest[t] * DIM;
    const float* r1 = eo + (size_t)dest[N_TOK + t] * DIM;
    int d = threadIdx.x * 4;
    float4 a = *(const float4*)(r0 + d);
    float4 b = *(const float4*)(r1 + d);
    float4 o;
    o.x = w0 * a.x + w1 * b.x;
    o.y = w0 * a.y + w1 * b.y;
    o.z = w0 * a.z + w1 * b.z;
    o.w = w0 * a.w + w1 * b.w;
    *(float4*)(out + (size_t)t * DIM + d) = o;
}

// ---------------------------------------------------------------------------
// Aux loss: deterministic fixed-tree reduction of probs mean + counts.
// ---------------------------------------------------------------------------
__global__ __launch_bounds__(256) void aux_kernel(const float* __restrict__ probs,
                                                  const int* __restrict__ counts,
                                                  float* __restrict__ out_aux) {
    __shared__ float sm[256][NEXP];
    float loc[NEXP];
#pragma unroll
    for (int e = 0; e < NEXP; ++e) loc[e] = 0.f;
    for (int t = threadIdx.x; t < N_TOK; t += 256)
#pragma unroll
        for (int e = 0; e < NEXP; ++e) loc[e] += probs[t * NEXP + e];
#pragma unroll
    for (int e = 0; e < NEXP; ++e) sm[threadIdx.x][e] = loc[e];
    __syncthreads();
    for (int s = 128; s > 0; s >>= 1) {
        if (threadIdx.x < s)
#pragma unroll
            for (int e = 0; e < NEXP; ++e) sm[threadIdx.x][e] += sm[threadIdx.x + s][e];
        __syncthreads();
    }
    if (threadIdx.x == 0) {
        int tot = 0;
        for (int e = 0; e < NEXP; ++e) tot += counts[e];
        float totf = tot > 0 ? (float)tot : 1.f;
        float aux = 0.f;
        for (int e = 0; e < NEXP; ++e)
            aux += ((float)counts[e] / totf) * (sm[0][e] / (float)N_TOK);
        out_aux[0] = 0.01f * (float)NEXP * aux;
    }
}

// ---------------------------------------------------------------------------
extern "C" void kernel_launch(void* const* d_in, const int* in_sizes, int n_in,
                              void* d_out, int out_size, void* d_ws, size_t ws_size,
                              hipStream_t stream) {
    const float* x  = (const float*)d_in[0];
    const float* Wr = (const float*)d_in[1];
    const float* Wg = (const float*)d_in[2];
    const float* Wu = (const float*)d_in[3];
    const float* Wd = (const float*)d_in[4];
    float* out = (float*)d_out;

    char* ws = (char*)d_ws;
    size_t off = 0;
    auto alloc = [&](size_t bytes) -> void* {
        void* p = ws + off;
        off += (bytes + 255) & ~(size_t)255;
        return p;
    };
    const size_t NW = (size_t)NEXP * FF * DIM;
    bf16*  Wg_bf = (bf16*)alloc(NW * sizeof(bf16));
    bf16*  Wu_bf = (bf16*)alloc(NW * sizeof(bf16));
    bf16*  Wd_bf = (bf16*)alloc(NW * sizeof(bf16));
    bf16*  Xe    = (bf16*)alloc((size_t)NEXP * CAP * DIM * sizeof(bf16));
    bf16*  hbuf  = (bf16*)alloc((size_t)NEXP * CAP * FF * sizeof(bf16));
    float* eo    = (float*)alloc((size_t)NEXP * CAP * DIM * sizeof(float));
    float* probs = (float*)alloc((size_t)N_TOK * NEXP * sizeof(float));
    int*   topi  = (int*)alloc((size_t)N_TOK * 2 * sizeof(int));
    float* topw  = (float*)alloc((size_t)N_TOK * 2 * sizeof(float));
    int*   dst   = (int*)alloc((size_t)NASSIGN * sizeof(int));
    int*   accf  = (int*)alloc((size_t)NASSIGN * sizeof(int));
    int*   cnts  = (int*)alloc(NEXP * sizeof(int));

    cvt_bf16_kernel<<<2048, 256, 0, stream>>>(Wg, Wg_bf, (int)NW);
    cvt_bf16_kernel<<<2048, 256, 0, stream>>>(Wu, Wu_bf, (int)NW);
    cvt_bf16_kernel<<<2048, 256, 0, stream>>>(Wd, Wd_bf, (int)NW);
    router_kernel<<<N_TOK / 4, 256, 0, stream>>>(x, Wr, probs, topi, topw);
    rank_kernel<<<NEXP, 64, 0, stream>>>(topi, dst, accf, cnts);
    gather_kernel<<<NASSIGN, 256, 0, stream>>>(x, dst, accf, Xe);
    gateup_kernel<<<dim3(CAP / 256, FF / 128, NEXP), 512, 0, stream>>>(Xe, Wg_bf, Wu_bf, hbuf);
    down_kernel<<<dim3(CAP / 128, DIM / 128, NEXP), 256, 0, stream>>>(hbuf, Wd_bf, eo);
    combine_kernel<<<N_TOK, 256, 0, stream>>>(eo, dst, accf, topw, out);
    aux_kernel<<<1, 256, 0, stream>>>(probs, cnts, out + (size_t)N_TOK * DIM);
}